// Round 14
// baseline (473.024 us; speedup 1.0000x reference)
//
#include <hip/hip_runtime.h>

// GCN 2-layer, CSR-by-dst gather formulation; h1s in bf16.
// R13: rank-1 c-term refactor. A_hat([x|mean]W1) = A_hat(xW1a) + q*c where
//      q[i] = dis[i]*sum_{src in N(i)} dis[src], c = mean@W1b.
//      -> bucketA loses the colsum job (pure multi-split, no x read);
//      -> csrBG computes colsums from the x tiles it already stages (bf16
//         partials, error ~5e-6 in mean) and transposes W1->LDS directly;
//      -> gather1 applies q*c in fp32 (per-edge dis[src] gather: L2-hot 400KB).
// gather1 at its measured floor (~45us: 4-deep and 8-deep MLP identical,
// FETCH pinned at 81 MB on the L2-miss path).
// out = A_hat( relu( A_hat( [x|mean]@W1 ) + b1 ) @ W2 ) + b2

#define NPB        256     // nodes per bucket
#define NPB_SHIFT  8
#define BKTS       512     // scan width (>= 391 buckets, pow2)
#define BKT_CAP    5120    // mean 4096 + 16 sigma
#define CHUNK      4096    // edges per bucketA block
#define EPT        8       // CHUNK / 512 threads
#define CUR_STRIDE 32      // ints per cursor slot (128-B line each)

using bf16x8 = __attribute__((ext_vector_type(8))) short;  // 8 bf16 (4 VGPRs)
using f32x4  = __attribute__((ext_vector_type(4))) float;

__device__ __forceinline__ unsigned short f2bf(float v) {
    unsigned u = __float_as_uint(v);
    u += 0x7FFFu + ((u >> 16) & 1u);   // round-to-nearest-even
    return (unsigned short)(u >> 16);
}
__device__ __forceinline__ float bf2f(unsigned short h) {
    return __uint_as_float((unsigned)h << 16);
}
// two bf16 packed in a uint -> two floats (2 VALU)
__device__ __forceinline__ float bfu_lo(unsigned u) { return __uint_as_float(u << 16); }
__device__ __forceinline__ float bfu_hi(unsigned u) { return __uint_as_float(u & 0xFFFF0000u); }

// ---------- pass A: pure LDS multi-split (packed 4-B records: src<<8 | dst&255) ----------
__global__ __launch_bounds__(512) void bucketA_kernel(
        const int* __restrict__ src, const int* __restrict__ dst,
        int e, unsigned* __restrict__ pairs, int* __restrict__ cursor) {
    __shared__ int cnt[BKTS], sb[BKTS], gpos[BKTS];
    __shared__ unsigned stage[CHUNK];
    __shared__ unsigned short bb[CHUNK];
    int tid = threadIdx.x;
    int chunkStart = blockIdx.x * CHUNK;
    int v = e - chunkStart;
    if (v > CHUNK) v = CHUNK;
    cnt[tid] = 0;
    __syncthreads();
    int myb[EPT], myoff[EPT];
    unsigned myp[EPT];
#pragma unroll
    for (int t = 0; t < EPT; ++t) {
        int i = chunkStart + t * 512 + tid;
        myb[t] = -1;
        if (i < e) {
            int s = src[i], d = dst[i];
            myb[t] = d >> NPB_SHIFT;
            myp[t] = ((unsigned)s << NPB_SHIFT) | (unsigned)(d & (NPB - 1));
            myoff[t] = atomicAdd(&cnt[myb[t]], 1);
        }
    }
    __syncthreads();
    sb[tid] = cnt[tid];
    __syncthreads();
    for (int off = 1; off < BKTS; off <<= 1) {
        int t = (tid >= off) ? sb[tid - off] : 0;
        __syncthreads();
        sb[tid] += t;
        __syncthreads();
    }
    {
        int excl = tid ? sb[tid - 1] : 0;
        int cb = cnt[tid];
        if (cb > 0) {
            int gb = atomicAdd(&cursor[tid * CUR_STRIDE], cb);  // private line
            gpos[tid] = tid * BKT_CAP + gb - excl;
        }
        cnt[tid] = excl;  // reuse as stage base
    }
    __syncthreads();
#pragma unroll
    for (int t = 0; t < EPT; ++t) {
        if (myb[t] >= 0) {
            int p = cnt[myb[t]] + myoff[t];
            stage[p] = myp[t];
            bb[p] = (unsigned short)myb[t];
        }
    }
    __syncthreads();
    for (int j = tid; j < v; j += 512) {
        int bk = bb[j];
        int wi = gpos[bk] + j;
        if (wi < (bk + 1) * BKT_CAP) pairs[wi] = stage[j];  // contiguous runs
    }
}

// ---------- pass B fused: CSR + dis + colsum partials + MFMA gemm (no c-term) ----------
__global__ __launch_bounds__(512) void csrBG_kernel(
        const unsigned* __restrict__ pairs, const int* __restrict__ cursor,
        float* __restrict__ dis, int* __restrict__ rowstart,
        int* __restrict__ eidx, int n,
        const float* __restrict__ W1, const float* __restrict__ x,
        unsigned short* __restrict__ h1s, float* __restrict__ sums) {
    __shared__ int ldeg[NPB];       // later reused as float dis bits
    __shared__ int lcur[NPB];
    __shared__ int scanbuf[512];
    __shared__ int s_ebase;
    __shared__ unsigned short Ws[64 * 72];       // W1a^T bf16, stride 72
    __shared__ unsigned short Xs[2][64 * 72];    // 2 tiles
    float* disl = (float*)ldeg;
    int b = blockIdx.x;
    int tid = threadIdx.x;
    int node0 = b << NPB_SHIFT;
    if (node0 >= n) return;
    int nl = n - node0;
    if (nl > NPB) nl = NPB;
    int cnt_b = cursor[b * CUR_STRIDE];
    if (cnt_b > BKT_CAP) cnt_b = BKT_CAP;
    if (tid < NPB) ldeg[tid] = 0;
    if (tid == 0) s_ebase = 0;
    __syncthreads();
    if (tid < b) atomicAdd(&s_ebase, cursor[tid * CUR_STRIDE]);  // parallel prefix
    const unsigned* mp = pairs + (size_t)b * BKT_CAP;
    for (int i = tid; i < cnt_b; i += 512)
        atomicAdd(&ldeg[mp[i] & (NPB - 1)], 1);
    __syncthreads();
    scanbuf[tid] = (tid < NPB) ? ldeg[tid] : 0;
    __syncthreads();
    for (int off = 1; off < 512; off <<= 1) {
        int t = (tid >= off) ? scanbuf[tid - off] : 0;
        __syncthreads();
        scanbuf[tid] += t;
        __syncthreads();
    }
    int ebase = s_ebase;
    int mydeg = 0;
    if (tid < NPB) {
        int ex = tid ? scanbuf[tid - 1] : 0;
        lcur[tid] = ex;
        mydeg = ldeg[tid];
        if (tid < nl) rowstart[node0 + tid] = ebase + ex;
    }
    if (tid == 0 && node0 + NPB >= n)          // last bucket: close the CSR
        rowstart[n] = ebase + cnt_b;
    __syncthreads();
    // overwrite ldeg with dis (float bits); hist/scan done, lcur carries cursors
    if (tid < NPB) {
        float dv = mydeg > 0 ? rsqrtf((float)mydeg) : 0.f;
        disl[tid] = dv;
        if (tid < nl) dis[node0 + tid] = dv;
    }
    for (int i = tid; i < cnt_b; i += 512) {
        unsigned p = mp[i];
        int pos = atomicAdd(&lcur[p & (NPB - 1)], 1);
        eidx[ebase + pos] = (int)(p >> NPB_SHIFT);  // contiguous ~16 KB window
    }
    // ---- stage W1a^T -> bf16 LDS (coalesced global read, one-time scatter) ----
    for (int i = tid; i < 4096; i += 512) {
        int k = i >> 6, j = i & 63;
        Ws[j * 72 + k] = f2bf(W1[i]);
    }
    // ---- gemm: 256 rows = 2 iters x 2 tiles x 64 rows; colsum partials fused ----
    int lane = tid & 63;
    int wv = tid >> 6;          // 0..7
    int tile = wv >> 2;         // 0..1
    int w4 = wv & 3;            // wave within tile
    int l15 = lane & 15;
    int quad = lane >> 4;
#pragma unroll
    for (int it = 0; it < 2; ++it) {
        __syncthreads();
        for (int i = tid; i < 2048; i += 512) {   // stage 128 rows of x -> bf16
            int r = i >> 4, k4 = (i & 15) * 4;
            int gr = node0 + it * 128 + r;
            float4 xv = make_float4(0.f, 0.f, 0.f, 0.f);
            if (gr < n) xv = *(const float4*)&x[(size_t)gr * 64 + k4];
            ushort4 hv;
            hv.x = f2bf(xv.x); hv.y = f2bf(xv.y); hv.z = f2bf(xv.z); hv.w = f2bf(xv.w);
            *(ushort4*)&Xs[r >> 6][(r & 63) * 72 + k4] = hv;
        }
        __syncthreads();
        // colsum partials from the staged tiles (rows >= n staged as 0)
        {
            int cj = tid & 63;
            int r0 = (tid >> 6) * 16;
            int ct = r0 >> 6;                 // constant tile for this thread
            float ps = 0.f;
#pragma unroll
            for (int rr = 0; rr < 16; ++rr)
                ps += bf2f(Xs[ct][((r0 + rr) & 63) * 72 + cj]);
            atomicAdd(&sums[cj], ps);
        }
        int xrow = w4 * 16 + l15;                    // row within tile
        f32x4 acc0 = {0.f, 0.f, 0.f, 0.f}, acc1 = acc0, acc2 = acc0, acc3 = acc0;
#pragma unroll
        for (int ks = 0; ks < 2; ++ks) {
            bf16x8 bfrag = *(const bf16x8*)&Xs[tile][xrow * 72 + ks * 32 + quad * 8];
            bf16x8 a0 = *(const bf16x8*)&Ws[(0 * 16 + l15) * 72 + ks * 32 + quad * 8];
            bf16x8 a1 = *(const bf16x8*)&Ws[(1 * 16 + l15) * 72 + ks * 32 + quad * 8];
            bf16x8 a2 = *(const bf16x8*)&Ws[(2 * 16 + l15) * 72 + ks * 32 + quad * 8];
            bf16x8 a3 = *(const bf16x8*)&Ws[(3 * 16 + l15) * 72 + ks * 32 + quad * 8];
            acc0 = __builtin_amdgcn_mfma_f32_16x16x32_bf16(a0, bfrag, acc0, 0, 0, 0);
            acc1 = __builtin_amdgcn_mfma_f32_16x16x32_bf16(a1, bfrag, acc1, 0, 0, 0);
            acc2 = __builtin_amdgcn_mfma_f32_16x16x32_bf16(a2, bfrag, acc2, 0, 0, 0);
            acc3 = __builtin_amdgcn_mfma_f32_16x16x32_bf16(a3, bfrag, acc3, 0, 0, 0);
        }
        int lrow = it * 128 + tile * 64 + xrow;      // row within bucket
        int grow = node0 + lrow;
        if (grow < n) {
            float dv = disl[lrow];
            f32x4 accs[4] = {acc0, acc1, acc2, acc3};
#pragma unroll
            for (int t = 0; t < 4; ++t) {
                ushort4 hs;
                hs.x = f2bf(accs[t][0] * dv);
                hs.y = f2bf(accs[t][1] * dv);
                hs.z = f2bf(accs[t][2] * dv);
                hs.w = f2bf(accs[t][3] * dv);
                *(ushort4*)&h1s[(size_t)grow * 64 + t * 16 + quad * 4] = hs;
            }
        }
    }
}

// ---------- layer-1 gather: 32 lanes/edge + fp32 rank-1 c-term (q = sum dis[src]) ----------
__global__ void gather1_kernel(const int* __restrict__ rowstart,
                               const int* __restrict__ eidx, const float* __restrict__ dis,
                               const unsigned short* __restrict__ h1s,
                               const float* __restrict__ b1, const float* __restrict__ W2,
                               const float* __restrict__ sums, const float* __restrict__ W1,
                               float* __restrict__ h2s, int n) {
    int lane = threadIdx.x & 63;
    int node = blockIdx.x * 4 + (threadIdx.x >> 6);
    if (node >= n) return;
    int sub = lane >> 5;        // edge subgroup 0..1
    int fp  = (lane & 31) * 2;  // feature pair base
    // c[fp], c[fp+1] = (sums/n) @ W1b columns (L1/L2-hot 16 KB)
    float c0 = 0.f, c1 = 0.f;
    for (int k = 0; k < 64; ++k) {
        float sk = sums[k];
        float2 wr = *(const float2*)&W1[(64 + k) * 64 + fp];
        c0 += sk * wr.x;
        c1 += sk * wr.y;
    }
    float inv_n = 1.0f / (float)n;
    c0 *= inv_n; c1 *= inv_n;
    int rs = rowstart[node];
    int re = rowstart[node + 1];
    int dn = re - rs;
    int m = dn < 64 ? dn : 64;
    int eHeld = (lane < m) ? eidx[rs + lane] : 0;  // one coalesced load for <=64 edges
    float qv = (lane < m) ? dis[eHeld] : 0.f;      // per-edge dis[src] (L2-hot 400 KB)
    float ax = 0.f, ay = 0.f;
    int j = 0;
    for (; j + 16 <= m; j += 16) {        // 16 edges per iter, 8 loads in flight
        int s0 = __shfl(eHeld, j + 0 + sub, 64);
        int s1 = __shfl(eHeld, j + 2 + sub, 64);
        int s2 = __shfl(eHeld, j + 4 + sub, 64);
        int s3 = __shfl(eHeld, j + 6 + sub, 64);
        int s4 = __shfl(eHeld, j + 8 + sub, 64);
        int s5 = __shfl(eHeld, j + 10 + sub, 64);
        int s6 = __shfl(eHeld, j + 12 + sub, 64);
        int s7 = __shfl(eHeld, j + 14 + sub, 64);
        unsigned u0 = *(const unsigned*)&h1s[((size_t)s0 << 6) + fp];
        unsigned u1 = *(const unsigned*)&h1s[((size_t)s1 << 6) + fp];
        unsigned u2 = *(const unsigned*)&h1s[((size_t)s2 << 6) + fp];
        unsigned u3 = *(const unsigned*)&h1s[((size_t)s3 << 6) + fp];
        unsigned u4 = *(const unsigned*)&h1s[((size_t)s4 << 6) + fp];
        unsigned u5 = *(const unsigned*)&h1s[((size_t)s5 << 6) + fp];
        unsigned u6 = *(const unsigned*)&h1s[((size_t)s6 << 6) + fp];
        unsigned u7 = *(const unsigned*)&h1s[((size_t)s7 << 6) + fp];
        ax += (bfu_lo(u0) + bfu_lo(u1)) + (bfu_lo(u2) + bfu_lo(u3))
            + (bfu_lo(u4) + bfu_lo(u5)) + (bfu_lo(u6) + bfu_lo(u7));
        ay += (bfu_hi(u0) + bfu_hi(u1)) + (bfu_hi(u2) + bfu_hi(u3))
            + (bfu_hi(u4) + bfu_hi(u5)) + (bfu_hi(u6) + bfu_hi(u7));
    }
    for (; j + 8 <= m; j += 8) {          // 8-edge tail, 4 loads
        int s0 = __shfl(eHeld, j + 0 + sub, 64);
        int s1 = __shfl(eHeld, j + 2 + sub, 64);
        int s2 = __shfl(eHeld, j + 4 + sub, 64);
        int s3 = __shfl(eHeld, j + 6 + sub, 64);
        unsigned u0 = *(const unsigned*)&h1s[((size_t)s0 << 6) + fp];
        unsigned u1 = *(const unsigned*)&h1s[((size_t)s1 << 6) + fp];
        unsigned u2 = *(const unsigned*)&h1s[((size_t)s2 << 6) + fp];
        unsigned u3 = *(const unsigned*)&h1s[((size_t)s3 << 6) + fp];
        ax += (bfu_lo(u0) + bfu_lo(u1)) + (bfu_lo(u2) + bfu_lo(u3));
        ay += (bfu_hi(u0) + bfu_hi(u1)) + (bfu_hi(u2) + bfu_hi(u3));
    }
    for (; j + 4 <= m; j += 4) {          // 4-edge tail, 2 loads
        int s0 = __shfl(eHeld, j + 0 + sub, 64);
        int s1 = __shfl(eHeld, j + 2 + sub, 64);
        unsigned u0 = *(const unsigned*)&h1s[((size_t)s0 << 6) + fp];
        unsigned u1 = *(const unsigned*)&h1s[((size_t)s1 << 6) + fp];
        ax += bfu_lo(u0) + bfu_lo(u1);
        ay += bfu_hi(u0) + bfu_hi(u1);
    }
    for (; j < m; j += 2) {               // ragged tail (0..1 edges per sub)
        int jj = j + sub;
        int s = __shfl(eHeld, jj < m ? jj : 0, 64);
        if (jj < m) {
            unsigned u = *(const unsigned*)&h1s[((size_t)s << 6) + fp];
            ax += bfu_lo(u);
            ay += bfu_hi(u);
        }
    }
    for (int t = 64; t < dn; ++t) {       // deg > 64: astronomically rare here
        if (sub == 0) {
            int s = eidx[rs + t];
            unsigned u = *(const unsigned*)&h1s[((size_t)s << 6) + fp];
            ax += bfu_lo(u);
            ay += bfu_hi(u);
            if (lane == 0) qv += dis[s];  // count each tail edge's dis once
        }
    }
    // reduce: feature sums across the 2 edge subgroups; q across all 64 lanes
    ax += __shfl_xor(ax, 32, 64);
    ay += __shfl_xor(ay, 32, 64);
#pragma unroll
    for (int off = 1; off <= 32; off <<= 1) qv += __shfl_xor(qv, off, 64);
    float di = dis[node];
    float2 bv = ((const float2*)b1)[lane & 31];
    float4 w = ((const float4*)W2)[lane & 31];   // W2[fp][0..1], W2[fp+1][0..1]
    float t0 = fmaxf(di * (ax + qv * c0) + bv.x, 0.f);
    float t1 = fmaxf(di * (ay + qv * c1) + bv.y, 0.f);
    float v0 = t0 * w.x + t1 * w.z;
    float v1 = t0 * w.y + t1 * w.w;
#pragma unroll
    for (int off = 1; off <= 16; off <<= 1) {   // sum the 32 feature classes
        v0 += __shfl_xor(v0, off, 64);
        v1 += __shfl_xor(v1, off, 64);
    }
    if (lane == 0) {
        h2s[(size_t)node * 2 + 0] = di * v0;
        h2s[(size_t)node * 2 + 1] = di * v1;
    }
}

// ---------- layer-2 gather: 16 lanes per node, one lane per edge ----------
__global__ void gather2_kernel(const int* __restrict__ rowstart,
                               const int* __restrict__ eidx, const float* __restrict__ dis,
                               const float2* __restrict__ h2s, const float* __restrict__ b2,
                               float2* __restrict__ out, int n) {
    int tid = threadIdx.x;
    int node = blockIdx.x * 16 + (tid >> 4);
    if (node >= n) return;
    int el = tid & 15;
    int rs = rowstart[node];
    int dn = rowstart[node + 1] - rs;
    float ax = 0.f, ay = 0.f;
    for (int t = el; t < dn; t += 16) {   // 16 edges in flight per node
        int s = eidx[rs + t];
        float2 h = h2s[s];
        ax += h.x;
        ay += h.y;
    }
#pragma unroll
    for (int off = 1; off <= 8; off <<= 1) {
        ax += __shfl_xor(ax, off, 64);
        ay += __shfl_xor(ay, off, 64);
    }
    if (el == 0) {
        float di = dis[node];
        out[node] = make_float2(di * ax + b2[0], di * ay + b2[1]);
    }
}

extern "C" void kernel_launch(void* const* d_in, const int* in_sizes, int n_in,
                              void* d_out, int out_size, void* d_ws, size_t ws_size,
                              hipStream_t stream) {
    const float* x  = (const float*)d_in[0];
    const int*   ei = (const int*)d_in[1];
    const float* W1 = (const float*)d_in[2];
    const float* b1 = (const float*)d_in[3];
    const float* W2 = (const float*)d_in[4];
    const float* b2 = (const float*)d_in[5];
    float2* out = (float2*)d_out;

    const int n = in_sizes[0] / 64;   // 100000
    const int e = in_sizes[1] / 2;    // 1600000
    const int* srcI = ei;
    const int* dstI = ei + e;
    const int nbkt = (n + NPB - 1) >> NPB_SHIFT;   // 391

    // workspace layout (256-B aligned segments); sums+cursor adjacent -> 1 memset
    char* p = (char*)d_ws;
    int* rowstart = (int*)p;    p += ((size_t)(n + 1) * 4 + 255) & ~255ull;
    float* dis    = (float*)p;  p += ((size_t)n * 4 + 255) & ~255ull;
    float* sums   = (float*)p;                  // 256 B
    int* cursor   = (int*)(p + 256);            // nbkt * 128-B padded slots
    size_t zsize  = 256 + (size_t)nbkt * CUR_STRIDE * 4;
    char* zbase   = p;          p += (zsize + 255) & ~255ull;
    int* eidx     = (int*)p;    p += ((size_t)e * 4 + 255) & ~255ull;
    unsigned* pairs = (unsigned*)p;  p += ((size_t)nbkt * BKT_CAP * 4 + 255) & ~255ull;
    unsigned short* h1s = (unsigned short*)p;  p += ((size_t)n * 64 * 2 + 255) & ~255ull;
    float* h2s    = (float*)p;

    hipMemsetAsync(zbase, 0, zsize, stream);

    const int nchunks = (e + CHUNK - 1) / CHUNK;           // 391

    bucketA_kernel<<<nchunks, 512, 0, stream>>>(srcI, dstI, e, pairs, cursor);
    csrBG_kernel<<<nbkt, 512, 0, stream>>>(pairs, cursor, dis, rowstart, eidx, n,
                                           W1, x, h1s, sums);
    gather1_kernel<<<(n + 3) / 4, 256, 0, stream>>>(rowstart, eidx, dis, h1s, b1, W2,
                                                    sums, W1, h2s, n);
    gather2_kernel<<<(n + 15) / 16, 256, 0, stream>>>(rowstart, eidx, dis, (const float2*)h2s,
                                                      b2, out, n);
}

// Round 15
// 187.415 us; speedup vs baseline: 2.5239x; 2.5239x over previous
//
#include <hip/hip_runtime.h>

// GCN 2-layer, CSR-by-dst gather formulation; h1s in bf16.
// R14: revert R13's per-wave c-recompute (load-serialized 64-iter prologue on
//      100K waves -> 211us gather1). Back to R12 structure: colsum in bucketAC,
//      c baked into h1s by csrBG (per-block cv, trivial). Cleanup: W^T staged
//      to LDS directly from W1 (no wtg round-trip / extra block).
// out = A_hat( relu( A_hat( [x|mean]@W1 ) + b1 ) @ W2 ) + b2
// Identity: [x|mean]@W1 = x@W1[:64] + c, c = mean@W1[64:].
// Pre-scaling: h1s[s] = dis[s]*(xW1a+c)[s];  h2s[s] = dis[s]*(relu(.)@W2)[s].

#define NPB        256     // nodes per bucket
#define NPB_SHIFT  8
#define BKTS       512     // scan width (>= 391 buckets, pow2)
#define BKT_CAP    5120    // mean 4096 + 16 sigma
#define CHUNK      4096    // edges per bucketA block
#define EPT        8       // CHUNK / 512 threads
#define CS_BLK     64      // colsum blocks prepended to bucketA grid
#define CUR_STRIDE 32      // ints per cursor slot (128-B line each)

using bf16x8 = __attribute__((ext_vector_type(8))) short;  // 8 bf16 (4 VGPRs)
using f32x4  = __attribute__((ext_vector_type(4))) float;

__device__ __forceinline__ unsigned short f2bf(float v) {
    unsigned u = __float_as_uint(v);
    u += 0x7FFFu + ((u >> 16) & 1u);   // round-to-nearest-even
    return (unsigned short)(u >> 16);
}
// two bf16 packed in a uint -> two floats (2 VALU)
__device__ __forceinline__ float bfu_lo(unsigned u) { return __uint_as_float(u << 16); }
__device__ __forceinline__ float bfu_hi(unsigned u) { return __uint_as_float(u & 0xFFFF0000u); }

// ---------- pass A: colsum (blocks 0..63) + LDS multi-split (rest) ----------
__global__ __launch_bounds__(512) void bucketAC_kernel(
        const int* __restrict__ src, const int* __restrict__ dst,
        int e, unsigned* __restrict__ pairs, int* __restrict__ cursor,
        const float* __restrict__ x, float* __restrict__ sums, int n) {
    int tid = threadIdx.x;
    if (blockIdx.x < CS_BLK) {
        // ---- colsum side-job: column sums of x via float4 grid-stride ----
        __shared__ float4 s4[512];
        int cb = blockIdx.x;
        const float4* x4 = (const float4*)x;
        int total4 = n * 16;
        float4 acc = make_float4(0.f, 0.f, 0.f, 0.f);
        // stride CS_BLK*512 = 32768 float4 == 0 mod 16 -> col group (i&15) fixed
        for (int i = cb * 512 + tid; i < total4; i += CS_BLK * 512) {
            float4 v = x4[i];
            acc.x += v.x; acc.y += v.y; acc.z += v.z; acc.w += v.w;
        }
        s4[tid] = acc;
        __syncthreads();
        if (tid < 16) {
            float4 v = s4[tid];
            for (int k = 1; k < 32; ++k) {
                float4 w = s4[tid + 16 * k];
                v.x += w.x; v.y += w.y; v.z += w.z; v.w += w.w;
            }
            atomicAdd(&sums[tid * 4 + 0], v.x);
            atomicAdd(&sums[tid * 4 + 1], v.y);
            atomicAdd(&sums[tid * 4 + 2], v.z);
            atomicAdd(&sums[tid * 4 + 3], v.w);
        }
        return;
    }
    // ---- bucket multi-split: packed 4-B records (src<<8 | dst&255) ----
    __shared__ int cnt[BKTS], sb[BKTS], gpos[BKTS];
    __shared__ unsigned stage[CHUNK];
    __shared__ unsigned short bb[CHUNK];
    int chunkStart = (blockIdx.x - CS_BLK) * CHUNK;
    int v = e - chunkStart;
    if (v > CHUNK) v = CHUNK;
    cnt[tid] = 0;
    __syncthreads();
    int myb[EPT], myoff[EPT];
    unsigned myp[EPT];
#pragma unroll
    for (int t = 0; t < EPT; ++t) {
        int i = chunkStart + t * 512 + tid;
        myb[t] = -1;
        if (i < e) {
            int s = src[i], d = dst[i];
            myb[t] = d >> NPB_SHIFT;
            myp[t] = ((unsigned)s << NPB_SHIFT) | (unsigned)(d & (NPB - 1));
            myoff[t] = atomicAdd(&cnt[myb[t]], 1);
        }
    }
    __syncthreads();
    sb[tid] = cnt[tid];
    __syncthreads();
    for (int off = 1; off < BKTS; off <<= 1) {
        int t = (tid >= off) ? sb[tid - off] : 0;
        __syncthreads();
        sb[tid] += t;
        __syncthreads();
    }
    {
        int excl = tid ? sb[tid - 1] : 0;
        int cb = cnt[tid];
        if (cb > 0) {
            int gb = atomicAdd(&cursor[tid * CUR_STRIDE], cb);  // private line
            gpos[tid] = tid * BKT_CAP + gb - excl;
        }
        cnt[tid] = excl;  // reuse as stage base
    }
    __syncthreads();
#pragma unroll
    for (int t = 0; t < EPT; ++t) {
        if (myb[t] >= 0) {
            int p = cnt[myb[t]] + myoff[t];
            stage[p] = myp[t];
            bb[p] = (unsigned short)myb[t];
        }
    }
    __syncthreads();
    for (int j = tid; j < v; j += 512) {
        int bk = bb[j];
        int wi = gpos[bk] + j;
        if (wi < (bk + 1) * BKT_CAP) pairs[wi] = stage[j];  // contiguous runs
    }
}

// ---------- pass B fused: CSR (hist+scan+fill) + cv + MFMA gemm for own rows ----------
__global__ __launch_bounds__(512) void csrBG_kernel(
        const unsigned* __restrict__ pairs, const int* __restrict__ cursor,
        float* __restrict__ dis, int* __restrict__ rowstart,
        int* __restrict__ eidx, int n,
        const float* __restrict__ sums, const float* __restrict__ W1,
        const float* __restrict__ x, unsigned short* __restrict__ h1s) {
    __shared__ int ldeg[NPB];       // later reused as float dis bits
    __shared__ int lcur[NPB];
    __shared__ int scanbuf[512];
    __shared__ int s_ebase;
    __shared__ __align__(16) float cv[64];
    __shared__ unsigned short Ws[64 * 72];       // W1a^T bf16, stride 72
    __shared__ unsigned short Xs[2][64 * 72];    // 2 tiles
    float* disl = (float*)ldeg;
    int b = blockIdx.x;
    int tid = threadIdx.x;
    int node0 = b << NPB_SHIFT;
    if (node0 >= n) return;
    int nl = n - node0;
    if (nl > NPB) nl = NPB;
    int cnt_b = cursor[b * CUR_STRIDE];
    if (cnt_b > BKT_CAP) cnt_b = BKT_CAP;
    if (tid < NPB) ldeg[tid] = 0;
    if (tid == 0) s_ebase = 0;
    __syncthreads();
    if (tid < b) atomicAdd(&s_ebase, cursor[tid * CUR_STRIDE]);  // parallel prefix
    const unsigned* mp = pairs + (size_t)b * BKT_CAP;
    for (int i = tid; i < cnt_b; i += 512)
        atomicAdd(&ldeg[mp[i] & (NPB - 1)], 1);
    __syncthreads();
    scanbuf[tid] = (tid < NPB) ? ldeg[tid] : 0;
    __syncthreads();
    for (int off = 1; off < 512; off <<= 1) {
        int t = (tid >= off) ? scanbuf[tid - off] : 0;
        __syncthreads();
        scanbuf[tid] += t;
        __syncthreads();
    }
    int ebase = s_ebase;
    int mydeg = 0;
    if (tid < NPB) {
        int ex = tid ? scanbuf[tid - 1] : 0;
        lcur[tid] = ex;
        mydeg = ldeg[tid];
        if (tid < nl) rowstart[node0 + tid] = ebase + ex;
    }
    if (tid == 0 && node0 + NPB >= n)          // last bucket: close the CSR
        rowstart[n] = ebase + cnt_b;
    __syncthreads();
    // overwrite ldeg with dis (float bits); hist/scan done, lcur carries cursors
    if (tid < NPB) {
        float dv = mydeg > 0 ? rsqrtf((float)mydeg) : 0.f;
        disl[tid] = dv;
        if (tid < nl) dis[node0 + tid] = dv;
    }
    for (int i = tid; i < cnt_b; i += 512) {
        unsigned p = mp[i];
        int pos = atomicAdd(&lcur[p & (NPB - 1)], 1);
        eidx[ebase + pos] = (int)(p >> NPB_SHIFT);  // contiguous ~16 KB window
    }
    // ---- cv = mean @ W1b (per-block, one-time, trivial) ----
    if (tid < 64) {
        float inv_n = 1.0f / (float)n;
        float acc = 0.f;
        for (int k = 0; k < 64; ++k) acc += (sums[k] * inv_n) * W1[(64 + k) * 64 + tid];
        cv[tid] = acc;
    }
    // ---- stage W1a^T -> bf16 LDS directly (coalesced read, one-time scatter) ----
    for (int i = tid; i < 4096; i += 512) {
        int k = i >> 6, j = i & 63;
        Ws[j * 72 + k] = f2bf(W1[i]);
    }
    // ---- gemm: 256 rows = 2 iters x 2 tiles x 64 rows ----
    int lane = tid & 63;
    int wv = tid >> 6;          // 0..7
    int tile = wv >> 2;         // 0..1
    int w4 = wv & 3;            // wave within tile
    int l15 = lane & 15;
    int quad = lane >> 4;
#pragma unroll
    for (int it = 0; it < 2; ++it) {
        __syncthreads();
        for (int i = tid; i < 2048; i += 512) {   // stage 128 rows of x -> bf16
            int r = i >> 4, k4 = (i & 15) * 4;
            int gr = node0 + it * 128 + r;
            float4 xv = make_float4(0.f, 0.f, 0.f, 0.f);
            if (gr < n) xv = *(const float4*)&x[(size_t)gr * 64 + k4];
            ushort4 hv;
            hv.x = f2bf(xv.x); hv.y = f2bf(xv.y); hv.z = f2bf(xv.z); hv.w = f2bf(xv.w);
            *(ushort4*)&Xs[r >> 6][(r & 63) * 72 + k4] = hv;
        }
        __syncthreads();
        int xrow = w4 * 16 + l15;                    // row within tile
        f32x4 acc0 = {0.f, 0.f, 0.f, 0.f}, acc1 = acc0, acc2 = acc0, acc3 = acc0;
#pragma unroll
        for (int ks = 0; ks < 2; ++ks) {
            bf16x8 bfrag = *(const bf16x8*)&Xs[tile][xrow * 72 + ks * 32 + quad * 8];
            bf16x8 a0 = *(const bf16x8*)&Ws[(0 * 16 + l15) * 72 + ks * 32 + quad * 8];
            bf16x8 a1 = *(const bf16x8*)&Ws[(1 * 16 + l15) * 72 + ks * 32 + quad * 8];
            bf16x8 a2 = *(const bf16x8*)&Ws[(2 * 16 + l15) * 72 + ks * 32 + quad * 8];
            bf16x8 a3 = *(const bf16x8*)&Ws[(3 * 16 + l15) * 72 + ks * 32 + quad * 8];
            acc0 = __builtin_amdgcn_mfma_f32_16x16x32_bf16(a0, bfrag, acc0, 0, 0, 0);
            acc1 = __builtin_amdgcn_mfma_f32_16x16x32_bf16(a1, bfrag, acc1, 0, 0, 0);
            acc2 = __builtin_amdgcn_mfma_f32_16x16x32_bf16(a2, bfrag, acc2, 0, 0, 0);
            acc3 = __builtin_amdgcn_mfma_f32_16x16x32_bf16(a3, bfrag, acc3, 0, 0, 0);
        }
        int lrow = it * 128 + tile * 64 + xrow;      // row within bucket
        int grow = node0 + lrow;
        if (grow < n) {
            float dv = disl[lrow];
            const float4* c4 = (const float4*)cv;
            f32x4 accs[4] = {acc0, acc1, acc2, acc3};
#pragma unroll
            for (int t = 0; t < 4; ++t) {
                float4 cj = c4[t * 4 + quad];
                ushort4 hs;
                hs.x = f2bf((accs[t][0] + cj.x) * dv);
                hs.y = f2bf((accs[t][1] + cj.y) * dv);
                hs.z = f2bf((accs[t][2] + cj.z) * dv);
                hs.w = f2bf((accs[t][3] + cj.w) * dv);
                *(ushort4*)&h1s[(size_t)grow * 64 + t * 16 + quad * 4] = hs;
            }
        }
    }
}

// ---------- layer-1 gather: 32 lanes/edge (ushort2/lane) — R12 measured form ----------
__global__ void gather1_kernel(const int* __restrict__ rowstart,
                               const int* __restrict__ eidx, const float* __restrict__ dis,
                               const unsigned short* __restrict__ h1s,
                               const float* __restrict__ b1, const float* __restrict__ W2,
                               float* __restrict__ h2s, int n) {
    int lane = threadIdx.x & 63;
    int node = blockIdx.x * 4 + (threadIdx.x >> 6);
    if (node >= n) return;
    int rs = rowstart[node];
    int re = rowstart[node + 1];
    int dn = re - rs;
    int m = dn < 64 ? dn : 64;
    int eHeld = (lane < m) ? eidx[rs + lane] : 0;  // one coalesced load for <=64 edges
    int sub = lane >> 5;        // edge subgroup 0..1
    int fp  = (lane & 31) * 2;  // feature pair base
    float ax = 0.f, ay = 0.f;
    int j = 0;
    for (; j + 16 <= m; j += 16) {        // 16 edges per iter, 8 loads in flight
        int s0 = __shfl(eHeld, j + 0 + sub, 64);
        int s1 = __shfl(eHeld, j + 2 + sub, 64);
        int s2 = __shfl(eHeld, j + 4 + sub, 64);
        int s3 = __shfl(eHeld, j + 6 + sub, 64);
        int s4 = __shfl(eHeld, j + 8 + sub, 64);
        int s5 = __shfl(eHeld, j + 10 + sub, 64);
        int s6 = __shfl(eHeld, j + 12 + sub, 64);
        int s7 = __shfl(eHeld, j + 14 + sub, 64);
        unsigned u0 = *(const unsigned*)&h1s[((size_t)s0 << 6) + fp];
        unsigned u1 = *(const unsigned*)&h1s[((size_t)s1 << 6) + fp];
        unsigned u2 = *(const unsigned*)&h1s[((size_t)s2 << 6) + fp];
        unsigned u3 = *(const unsigned*)&h1s[((size_t)s3 << 6) + fp];
        unsigned u4 = *(const unsigned*)&h1s[((size_t)s4 << 6) + fp];
        unsigned u5 = *(const unsigned*)&h1s[((size_t)s5 << 6) + fp];
        unsigned u6 = *(const unsigned*)&h1s[((size_t)s6 << 6) + fp];
        unsigned u7 = *(const unsigned*)&h1s[((size_t)s7 << 6) + fp];
        ax += (bfu_lo(u0) + bfu_lo(u1)) + (bfu_lo(u2) + bfu_lo(u3))
            + (bfu_lo(u4) + bfu_lo(u5)) + (bfu_lo(u6) + bfu_lo(u7));
        ay += (bfu_hi(u0) + bfu_hi(u1)) + (bfu_hi(u2) + bfu_hi(u3))
            + (bfu_hi(u4) + bfu_hi(u5)) + (bfu_hi(u6) + bfu_hi(u7));
    }
    for (; j + 8 <= m; j += 8) {          // 8-edge tail, 4 loads
        int s0 = __shfl(eHeld, j + 0 + sub, 64);
        int s1 = __shfl(eHeld, j + 2 + sub, 64);
        int s2 = __shfl(eHeld, j + 4 + sub, 64);
        int s3 = __shfl(eHeld, j + 6 + sub, 64);
        unsigned u0 = *(const unsigned*)&h1s[((size_t)s0 << 6) + fp];
        unsigned u1 = *(const unsigned*)&h1s[((size_t)s1 << 6) + fp];
        unsigned u2 = *(const unsigned*)&h1s[((size_t)s2 << 6) + fp];
        unsigned u3 = *(const unsigned*)&h1s[((size_t)s3 << 6) + fp];
        ax += (bfu_lo(u0) + bfu_lo(u1)) + (bfu_lo(u2) + bfu_lo(u3));
        ay += (bfu_hi(u0) + bfu_hi(u1)) + (bfu_hi(u2) + bfu_hi(u3));
    }
    for (; j + 4 <= m; j += 4) {          // 4-edge tail, 2 loads
        int s0 = __shfl(eHeld, j + 0 + sub, 64);
        int s1 = __shfl(eHeld, j + 2 + sub, 64);
        unsigned u0 = *(const unsigned*)&h1s[((size_t)s0 << 6) + fp];
        unsigned u1 = *(const unsigned*)&h1s[((size_t)s1 << 6) + fp];
        ax += bfu_lo(u0) + bfu_lo(u1);
        ay += bfu_hi(u0) + bfu_hi(u1);
    }
    for (; j < m; j += 2) {               // ragged tail (0..1 edges per sub)
        int jj = j + sub;
        int s = __shfl(eHeld, jj < m ? jj : 0, 64);
        if (jj < m) {
            unsigned u = *(const unsigned*)&h1s[((size_t)s << 6) + fp];
            ax += bfu_lo(u);
            ay += bfu_hi(u);
        }
    }
    for (int t = 64; t < dn; ++t) {       // deg > 64: astronomically rare here
        if (sub == 0) {
            int s = eidx[rs + t];
            unsigned u = *(const unsigned*)&h1s[((size_t)s << 6) + fp];
            ax += bfu_lo(u);
            ay += bfu_hi(u);
        }
    }
    // reduce across the 2 edge subgroups (both halves end with full sums)
    ax += __shfl_xor(ax, 32, 64);
    ay += __shfl_xor(ay, 32, 64);
    float di = dis[node];
    float2 bv = ((const float2*)b1)[lane & 31];
    float4 w = ((const float4*)W2)[lane & 31];   // W2[fp][0..1], W2[fp+1][0..1]
    float t0 = fmaxf(di * ax + bv.x, 0.f);
    float t1 = fmaxf(di * ay + bv.y, 0.f);
    float v0 = t0 * w.x + t1 * w.z;
    float v1 = t0 * w.y + t1 * w.w;
#pragma unroll
    for (int off = 1; off <= 16; off <<= 1) {   // sum the 32 feature classes
        v0 += __shfl_xor(v0, off, 64);
        v1 += __shfl_xor(v1, off, 64);
    }
    if (lane == 0) {
        h2s[(size_t)node * 2 + 0] = di * v0;
        h2s[(size_t)node * 2 + 1] = di * v1;
    }
}

// ---------- layer-2 gather: 16 lanes per node, one lane per edge ----------
__global__ void gather2_kernel(const int* __restrict__ rowstart,
                               const int* __restrict__ eidx, const float* __restrict__ dis,
                               const float2* __restrict__ h2s, const float* __restrict__ b2,
                               float2* __restrict__ out, int n) {
    int tid = threadIdx.x;
    int node = blockIdx.x * 16 + (tid >> 4);
    if (node >= n) return;
    int el = tid & 15;
    int rs = rowstart[node];
    int dn = rowstart[node + 1] - rs;
    float ax = 0.f, ay = 0.f;
    for (int t = el; t < dn; t += 16) {   // 16 edges in flight per node
        int s = eidx[rs + t];
        float2 h = h2s[s];
        ax += h.x;
        ay += h.y;
    }
#pragma unroll
    for (int off = 1; off <= 8; off <<= 1) {
        ax += __shfl_xor(ax, off, 64);
        ay += __shfl_xor(ay, off, 64);
    }
    if (el == 0) {
        float di = dis[node];
        out[node] = make_float2(di * ax + b2[0], di * ay + b2[1]);
    }
}

extern "C" void kernel_launch(void* const* d_in, const int* in_sizes, int n_in,
                              void* d_out, int out_size, void* d_ws, size_t ws_size,
                              hipStream_t stream) {
    const float* x  = (const float*)d_in[0];
    const int*   ei = (const int*)d_in[1];
    const float* W1 = (const float*)d_in[2];
    const float* b1 = (const float*)d_in[3];
    const float* W2 = (const float*)d_in[4];
    const float* b2 = (const float*)d_in[5];
    float2* out = (float2*)d_out;

    const int n = in_sizes[0] / 64;   // 100000
    const int e = in_sizes[1] / 2;    // 1600000
    const int* srcI = ei;
    const int* dstI = ei + e;
    const int nbkt = (n + NPB - 1) >> NPB_SHIFT;   // 391

    // workspace layout (256-B aligned segments); sums+cursor adjacent -> 1 memset
    char* p = (char*)d_ws;
    int* rowstart = (int*)p;    p += ((size_t)(n + 1) * 4 + 255) & ~255ull;
    float* dis    = (float*)p;  p += ((size_t)n * 4 + 255) & ~255ull;
    float* sums   = (float*)p;                  // 256 B
    int* cursor   = (int*)(p + 256);            // nbkt * 128-B padded slots
    size_t zsize  = 256 + (size_t)nbkt * CUR_STRIDE * 4;
    char* zbase   = p;          p += (zsize + 255) & ~255ull;
    int* eidx     = (int*)p;    p += ((size_t)e * 4 + 255) & ~255ull;
    unsigned* pairs = (unsigned*)p;  p += ((size_t)nbkt * BKT_CAP * 4 + 255) & ~255ull;
    unsigned short* h1s = (unsigned short*)p;  p += ((size_t)n * 64 * 2 + 255) & ~255ull;
    float* h2s    = (float*)p;

    hipMemsetAsync(zbase, 0, zsize, stream);

    const int nchunks = (e + CHUNK - 1) / CHUNK;           // 391

    bucketAC_kernel<<<CS_BLK + nchunks, 512, 0, stream>>>(srcI, dstI, e, pairs, cursor,
                                                          x, sums, n);
    csrBG_kernel<<<nbkt, 512, 0, stream>>>(pairs, cursor, dis, rowstart, eidx, n,
                                           sums, W1, x, h1s);
    gather1_kernel<<<(n + 3) / 4, 256, 0, stream>>>(rowstart, eidx, dis, h1s, b1, W2, h2s, n);
    gather2_kernel<<<(n + 15) / 16, 256, 0, stream>>>(rowstart, eidx, dis, (const float2*)h2s,
                                                      b2, out, n);
}